// Round 1
// baseline (605.433 us; speedup 1.0000x reference)
//
#include <hip/hip_runtime.h>
#include <cstddef>

#define Bc   32
#define Nc   512
#define Mc   512
#define DFc  64
#define BIGC 1.0e10f

// ---------------------------------------------------------------------------
// Kernel 1: D[b][n][m] = sum_k (X[b,n,k] - Y[b,m,k])^2
// Tile: 128 rows (n) x 64 cols (m), block = 256 threads (16x16),
// microtile 8x4 per thread. LDS rows padded to 68 floats (16B-aligned rows,
// lane bank-stride 4 -> <=2-way conflicts, which are free on gfx950).
// ---------------------------------------------------------------------------
__global__ __launch_bounds__(256) void dist_kernel(
    const float* __restrict__ X, const float* __restrict__ Y,
    float* __restrict__ D)
{
    __shared__ __align__(16) float Xs[128][68];
    __shared__ __align__(16) float Ys[64][68];

    const int b  = blockIdx.z;
    const int n0 = blockIdx.y * 128;
    const int m0 = blockIdx.x * 64;
    const int tid = threadIdx.x;

    const float* Xg = X + ((size_t)b * Nc + n0) * DFc;
    const float* Yg = Y + ((size_t)b * Mc + m0) * DFc;

    // Stage slabs: consecutive lanes -> consecutive k -> coalesced global,
    // LDS write addr = n*68 + lane -> conflict-free.
#pragma unroll
    for (int it = 0; it < 32; ++it) {
        int e = it * 256 + tid;
        int n = e >> 6, k = e & 63;
        Xs[n][k] = Xg[e];
    }
#pragma unroll
    for (int it = 0; it < 16; ++it) {
        int e = it * 256 + tid;
        int n = e >> 6, k = e & 63;
        Ys[n][k] = Yg[e];
    }
    __syncthreads();

    const int tx = tid & 15;   // column group
    const int ty = tid >> 4;   // row group

    float acc[8][4];
#pragma unroll
    for (int a = 0; a < 8; ++a)
#pragma unroll
        for (int c = 0; c < 4; ++c) acc[a][c] = 0.0f;

#pragma unroll
    for (int k4 = 0; k4 < 16; ++k4) {
        float4 xv[8], yv[4];
#pragma unroll
        for (int a = 0; a < 8; ++a)
            xv[a] = *(const float4*)&Xs[ty + 16 * a][k4 * 4];
#pragma unroll
        for (int c = 0; c < 4; ++c)
            yv[c] = *(const float4*)&Ys[tx + 16 * c][k4 * 4];
#pragma unroll
        for (int a = 0; a < 8; ++a) {
#pragma unroll
            for (int c = 0; c < 4; ++c) {
                float d0 = xv[a].x - yv[c].x;
                float d1 = xv[a].y - yv[c].y;
                float d2 = xv[a].z - yv[c].z;
                float d3 = xv[a].w - yv[c].w;
                acc[a][c] = fmaf(d0, d0,
                            fmaf(d1, d1,
                            fmaf(d2, d2,
                            fmaf(d3, d3, acc[a][c]))));
            }
        }
    }

    // Store: lanes tx consecutive -> coalesced 64B groups per row.
#pragma unroll
    for (int a = 0; a < 8; ++a) {
        int n = n0 + ty + 16 * a;
        float* Drow = D + ((size_t)b * Nc + n) * Mc + m0;
#pragma unroll
        for (int c = 0; c < 4; ++c) {
            Drow[tx + 16 * c] = acc[a][c];
        }
    }
}

// ---------------------------------------------------------------------------
// Kernel 2: anti-diagonal wavefront soft-DTW scan.
// One block (512 threads) per batch; thread t owns row i = t+1.
// Three rotating LDS diagonals; one __syncthreads per diagonal.
//   cur[i] = D[i-1][j-1] + softmin(A[i-1], B[i-1], B[i]),  j = d - i
// softmin(a,b,c) = m - log(exp(m-a)+exp(m-b)+exp(m-c)),   m = min(a,b,c)
// Output: out[b] = R[xl, yl] picked up at d == xl+yl, i == xl.
// ---------------------------------------------------------------------------
__global__ __launch_bounds__(512) void scan_kernel(
    const float* __restrict__ D,
    const int* __restrict__ X_len, const int* __restrict__ Y_len,
    float* __restrict__ out)
{
    __shared__ float buf0[516];
    __shared__ float buf1[516];
    __shared__ float buf2[516];

    const int b = blockIdx.x;
    const int t = threadIdx.x;   // 0..511
    const int i = t + 1;         // row 1..512

    const int xl = X_len[b];
    const int yl = Y_len[b];
    const int dmax = xl + yl;    // in [768, 1024]

    // diag 0: R[0,0]=0, rest BIG.  diag 1: all BIG.
    buf0[t] = (t == 0) ? 0.0f : BIGC;
    buf1[t] = BIGC;
    if (t == 511) { buf0[512] = BIGC; buf1[512] = BIGC; }
    __syncthreads();

    const float* Db = D + (size_t)b * Nc * Mc;
    const float* Drow = Db + (size_t)(i - 1) * Mc;

    float* A  = buf0;   // diag d-2
    float* Bv = buf1;   // diag d-1
    float* C  = buf2;   // diag d (write target)

    // Prefetch D for d=2 (clamped address; unused value when j invalid).
    int j0 = 2 - i;
    float Dv = Drow[min(max(j0, 1), Mc) - 1];

    for (int d = 2; d <= dmax; ++d) {
        // Prefetch next diagonal's D element (per-thread sequential address).
        int jn = d + 1 - i;
        float Dv_next = Drow[min(max(jn, 1), Mc) - 1];

        int j = d - i;
        float a  = A[i - 1];
        float b1 = Bv[i - 1];
        float b2 = Bv[i];

        float m3   = fminf(a, fminf(b1, b2));
        float s    = __expf(m3 - a) + __expf(m3 - b1) + __expf(m3 - b2);
        float soft = m3 - __logf(s);

        float cur = (j >= 1 && j <= Mc) ? (Dv + soft) : BIGC;

        C[i] = cur;
        if (t == 0) C[0] = BIGC;   // border R[0, d] = BIG

        if (d == dmax && i == xl) out[b] = cur;

        __syncthreads();   // separates this iter's reads from next iter's
                           // write into the recycled (oldest) buffer

        // rotate buffers
        float* tmp = A; A = Bv; Bv = C; C = tmp;
        Dv = Dv_next;
    }
}

extern "C" void kernel_launch(void* const* d_in, const int* in_sizes, int n_in,
                              void* d_out, int out_size, void* d_ws, size_t ws_size,
                              hipStream_t stream)
{
    const float* X  = (const float*)d_in[0];
    const float* Y  = (const float*)d_in[1];
    const int*   xl = (const int*)d_in[2];
    const int*   yl = (const int*)d_in[3];
    float* out = (float*)d_out;
    float* D   = (float*)d_ws;   // 32*512*512*4 = 33.5 MB scratch

    dist_kernel<<<dim3(Mc / 64, Nc / 128, Bc), 256, 0, stream>>>(X, Y, D);
    scan_kernel<<<Bc, 512, 0, stream>>>(D, xl, yl, out);
}

// Round 2
// 358.468 us; speedup vs baseline: 1.6889x; 1.6889x over previous
//
#include <hip/hip_runtime.h>
#include <hip/hip_fp16.h>
#include <cstddef>

#define Bc   32
#define Nc   512
#define Mc   512
#define DFc  64
#define BIGC 1.0e10f
#define LOG2E_F 1.4426950408889634f
#define LN2_F   0.6931471805599453f

typedef unsigned int uint32;

// lane l gets lane l-1's src; lane 0 gets `oldv`  (DPP wave_shr1, gfx9-lineage)
__device__ __forceinline__ float dpp_shr1(float oldv, float src) {
    return __int_as_float(__builtin_amdgcn_update_dpp(
        __float_as_int(oldv), __float_as_int(src), 0x138, 0xf, 0xf, false));
}

// ---------------------------------------------------------------------------
// Kernel 1: distances, written in SKEWED fp16 layout for the scan:
//   Dsk[tile][p][l] = half2( D[64w+l][64J + (2p-l)], D[64w+l][64J + (2p+1-l)] )
// tile = (b*8 + w)*8 + J ; invalid halves (c outside [0,64)) are garbage and
// never read by the scan (validity matches the scan's active predicate).
// Block: 256 threads computes a 128(row)x64(col) slab = 2 scan tiles.
// ---------------------------------------------------------------------------
__global__ __launch_bounds__(256) void dist_kernel(
    const float* __restrict__ X, const float* __restrict__ Y,
    uint32* __restrict__ Dsk)
{
    __shared__ __align__(16) float Xs[128][68];
    __shared__ __align__(16) float Ys[64][68];

    const int b  = blockIdx.z;
    const int n0 = blockIdx.y * 128;
    const int m0 = blockIdx.x * 64;
    const int tid = threadIdx.x;

    const float* Xg = X + ((size_t)b * Nc + n0) * DFc;
    const float* Yg = Y + ((size_t)b * Mc + m0) * DFc;

    // Stage slabs with float4 (coalesced; 16B-aligned LDS rows, stride 68)
#pragma unroll
    for (int it = 0; it < 8; ++it) {
        int e4 = it * 256 + tid;
        int n = e4 >> 4, k = (e4 & 15) * 4;
        *(float4*)&Xs[n][k] = *(const float4*)&Xg[e4 * 4];
    }
#pragma unroll
    for (int it = 0; it < 4; ++it) {
        int e4 = it * 256 + tid;
        int n = e4 >> 4, k = (e4 & 15) * 4;
        *(float4*)&Ys[n][k] = *(const float4*)&Yg[e4 * 4];
    }
    __syncthreads();

    const int tx = tid & 15;
    const int ty = tid >> 4;

    float acc[8][4];
#pragma unroll
    for (int a = 0; a < 8; ++a)
#pragma unroll
        for (int c = 0; c < 4; ++c) acc[a][c] = 0.0f;

#pragma unroll
    for (int k4 = 0; k4 < 16; ++k4) {
        float4 xv[8], yv[4];
#pragma unroll
        for (int a = 0; a < 8; ++a)
            xv[a] = *(const float4*)&Xs[ty + 16 * a][k4 * 4];
#pragma unroll
        for (int c = 0; c < 4; ++c)
            yv[c] = *(const float4*)&Ys[tx + 16 * c][k4 * 4];
#pragma unroll
        for (int a = 0; a < 8; ++a) {
#pragma unroll
            for (int c = 0; c < 4; ++c) {
                float d0 = xv[a].x - yv[c].x;
                float d1 = xv[a].y - yv[c].y;
                float d2 = xv[a].z - yv[c].z;
                float d3 = xv[a].w - yv[c].w;
                acc[a][c] = fmaf(d0, d0,
                            fmaf(d1, d1,
                            fmaf(d2, d2,
                            fmaf(d3, d3, acc[a][c]))));
            }
        }
    }
    __syncthreads();   // done reading Xs/Ys; alias Xs as Ct

    // Ct[128][66] (stride 66: write banks 2-way, diagonal reads odd-stride 65)
    float* Ct = (float*)Xs;
#pragma unroll
    for (int a = 0; a < 8; ++a) {
        int r = ty + 16 * a;
#pragma unroll
        for (int c = 0; c < 4; ++c)
            Ct[r * 66 + tx + 16 * c] = acc[a][c];
    }
    __syncthreads();

    // Skewed fp16 write: 2 sub-tiles (w2), thread handles (p = pq+4*it, lane l)
    const int l  = tid & 63;
    const int pq = tid >> 6;   // 0..3
#pragma unroll
    for (int w2 = 0; w2 < 2; ++w2) {
        uint32* outt = Dsk + (((size_t)b * 8 + (2 * blockIdx.y + w2)) * 8 + blockIdx.x) * 4096;
        const float* Crow = Ct + (w2 * 64 + l) * 66;
#pragma unroll
        for (int it = 0; it < 16; ++it) {
            int p = pq + 4 * it;
            int c0 = 2 * p - l;
            float f0 = Crow[min(max(c0, 0), 63)];
            float f1 = Crow[min(max(c0 + 1, 0), 63)];
            __half2 h = __floats2half2_rn(f0, f1);
            outt[p * 64 + l] = *(uint32*)&h;
        }
    }
}

// ---------------------------------------------------------------------------
// Kernel 2: tile-systolic soft-DTW scan.
// 1 block (8 waves) per batch. Wave w owns rows 64w+1..64w+64 (lane l -> row
// i0+l+1). Tiles 64x64; 15 barrier-separated tile-steps; inside a tile,
// 128 shuffle(DPP)+softmin steps, D from global (coalesced skewed fp16,
// 8-pair register prefetch), frontier row H in LDS (4-pair prefetch).
// ---------------------------------------------------------------------------
#define DTW_STEP(Dv, Hv, FIRSTH)                                              \
  {                                                                           \
    float upc = dpp_shr1(Hv, cur);                                            \
    float dg, lt;                                                             \
    if (FIRSTH) {                                                             \
      bool fst = (s == c1);                                                   \
      dg = fst ? LfUp : diag;                                                 \
      lt = fst ? Lf : cur;                                                    \
    } else {                                                                  \
      dg = diag; lt = cur;                                                    \
    }                                                                         \
    float mn = fminf(fminf(dg, upc), lt);                                     \
    float mc = mn * LOG2E_F;                                                  \
    float e = exp2f(fmaf(dg,  -LOG2E_F, mc))                                  \
            + exp2f(fmaf(upc, -LOG2E_F, mc))                                  \
            + exp2f(fmaf(lt,  -LOG2E_F, mc));                                 \
    float val = fmaf(log2f(e), -LN2_F, mn) + (Dv);                            \
    if (!FIRSTH) Lfnext = (s == c2) ? val : Lfnext;                           \
    diag = upc; cur = val;                                                    \
    bool swin = (s >= 64) && (s <= 127);                                      \
    float* hp = (is63 && swin) ? (hreal + s) : hdumpl;                        \
    *hp = val;                                                                \
    if (capt && s == scap)                                                    \
      outv = __int_as_float(__builtin_amdgcn_readlane(__float_as_int(val), lxl)); \
    ++s;                                                                      \
  }

__global__ __launch_bounds__(512) void scan_kernel(
    const uint32* __restrict__ Dsk,
    const int* __restrict__ X_len, const int* __restrict__ Y_len,
    float* __restrict__ out)
{
    // H: [0..512] frontier, [513..663] overread scratch, [664..727] dump
    __shared__ float Hs[728];

    const int tid = threadIdx.x;
    const int l = tid & 63, w = tid >> 6;
    const int b = blockIdx.x;

    const int xl = X_len[b], yl = Y_len[b];
    const int lxl = (xl - 1) & 63, wxl = (xl - 1) >> 6;
    const int Jcap = (yl - 1) >> 6;

    Hs[tid] = (tid == 0) ? 0.0f : BIGC;
    if (tid < 216) Hs[512 + tid] = BIGC;
    __syncthreads();

    float* hdumpl = &Hs[664 + l];
    const bool is63 = (l == 63);
    const int c1 = l + 1, c2 = l + 64;
    const bool capture_wave = (w == wxl);

    float Lf = BIGC;
    float corner = (w == 0) ? 0.0f : BIGC;
    float outv = 0.0f;

    for (int k = 0; k < 15; ++k) {
        int J = k - w;
        if (0 <= J && J < 8) {
            const int j0 = J << 6;
            // corner of NEXT tile: row 64w value at col j0+64, stable now,
            // clobbered by our own lane63 at inner step 127 -> read first.
            float cornerNext = Hs[j0 + 64];
            float LfUp = dpp_shr1(corner, Lf);
            float* hreal = &Hs[j0 - 63];   // hreal[s] valid for s in [64,127]

            const uint32* tp = Dsk + ((((size_t)b * 8 + w) * 8) + J) * 4096 + l;

            uint32 dbuf[8];
#pragma unroll
            for (int q = 0; q < 8; ++q) dbuf[q] = tp[q * 64];
            float hb[8];
#pragma unroll
            for (int q = 0; q < 4; ++q) {
                hb[2 * q]     = Hs[j0 + 2 * q + 1];
                hb[2 * q + 1] = Hs[j0 + 2 * q + 2];
            }

            float cur = BIGC, diag = BIGC, Lfnext = BIGC;
            bool capt = capture_wave && (J == Jcap);
            int scap = capt ? (yl - j0 + lxl) : -1;
            int s = 1;

            // ---- first half: pairs 0..31  (s = 1..64) ----
            for (int m = 0; m < 4; ++m) {
                const uint32* tpm = tp + (m * 8 + 8) * 64;
#pragma unroll
                for (int q = 0; q < 8; ++q) {
                    int p = m * 8 + q;
                    uint32 du = dbuf[q];
                    __half2 h2 = *(__half2*)&du;
                    float2 df = __half22float2(h2);
                    float h1v = hb[(q & 3) * 2], h2v = hb[(q & 3) * 2 + 1];
                    DTW_STEP(df.x, h1v, true)
                    DTW_STEP(df.y, h2v, true)
                    dbuf[q] = tpm[q * 64];                 // pair p+8
                    int hidx = j0 + 2 * (p + 4) + 1;       // pair p+4
                    hb[(q & 3) * 2]     = Hs[hidx];
                    hb[(q & 3) * 2 + 1] = Hs[hidx + 1];
                }
            }
            float Lf0 = cur;   // lane 0's right-column value (its s=64 val)

            // ---- second half A: pairs 32..55 (s = 65..112), with D prefetch ----
            for (int m = 0; m < 3; ++m) {
                const uint32* tpm = tp + (32 + m * 8 + 8) * 64;
#pragma unroll
                for (int q = 0; q < 8; ++q) {
                    int p = 32 + m * 8 + q;
                    uint32 du = dbuf[q];
                    __half2 h2 = *(__half2*)&du;
                    float2 df = __half22float2(h2);
                    float h1v = hb[(q & 3) * 2], h2v = hb[(q & 3) * 2 + 1];
                    DTW_STEP(df.x, h1v, false)
                    DTW_STEP(df.y, h2v, false)
                    dbuf[q] = tpm[q * 64];
                    int hidx = j0 + 2 * (p + 4) + 1;       // in-bounds scratch
                    hb[(q & 3) * 2]     = Hs[hidx];
                    hb[(q & 3) * 2 + 1] = Hs[hidx + 1];
                }
            }
            // ---- final: pairs 56..63 (s = 113..128), no D prefetch ----
            {
#pragma unroll
                for (int q = 0; q < 8; ++q) {
                    uint32 du = dbuf[q];
                    __half2 h2 = *(__half2*)&du;
                    float2 df = __half22float2(h2);
                    float h1v = hb[(q & 3) * 2], h2v = hb[(q & 3) * 2 + 1];
                    DTW_STEP(df.x, h1v, false)
                    DTW_STEP(df.y, h2v, false)
                }
            }

            Lfnext = (l == 0) ? Lf0 : Lfnext;
            Lf = Lfnext;
            corner = cornerNext;
        }
        __syncthreads();
    }

    if (capture_wave && l == 0) out[b] = outv;
}

extern "C" void kernel_launch(void* const* d_in, const int* in_sizes, int n_in,
                              void* d_out, int out_size, void* d_ws, size_t ws_size,
                              hipStream_t stream)
{
    const float* X  = (const float*)d_in[0];
    const float* Y  = (const float*)d_in[1];
    const int*   xl = (const int*)d_in[2];
    const int*   yl = (const int*)d_in[3];
    float* out = (float*)d_out;
    uint32* Dsk = (uint32*)d_ws;   // 32 * 64 tiles * 64 pairs * 64 lanes * 4 B = 33.5 MB

    dist_kernel<<<dim3(8, 4, Bc), 256, 0, stream>>>(X, Y, Dsk);
    scan_kernel<<<Bc, 512, 0, stream>>>(Dsk, xl, yl, out);
}

// Round 3
// 341.850 us; speedup vs baseline: 1.7710x; 1.0486x over previous
//
#include <hip/hip_runtime.h>
#include <hip/hip_fp16.h>
#include <cstddef>

#define Bc   32
#define Nc   512
#define Mc   512
#define DFc  64
#define BIGC 1.0e10f
#define LOG2E_F 1.4426950408889634f
#define LN2_F   0.6931471805599453f

typedef unsigned int uint32;

// lane l gets lane l-1's src; lane 0 gets `oldv`  (DPP wave_shr:1)
__device__ __forceinline__ float dpp_shr1(float oldv, float src) {
    return __int_as_float(__builtin_amdgcn_update_dpp(
        __float_as_int(oldv), __float_as_int(src), 0x138, 0xf, 0xf, false));
}

// ---------------------------------------------------------------------------
// Kernel 1: distances in SCALED (x LOG2E) fp16, skewed dwordx4 layout:
//   tile = (b*8 + w)*8 + J   (w = row strip, J = col strip)
//   uint4 at [tile*1024 + pg*64 + l], component e = pair p = 4*pg+e:
//     half2( D[64w+l][64J + (2p-l)], D[64w+l][64J + (2p+1-l)] ) * LOG2E
//   out-of-range halves are clamped garbage, never consumed by the scan.
// Block: 256 threads computes a 128(row)x64(col) slab = 2 scan tiles.
// ---------------------------------------------------------------------------
__global__ __launch_bounds__(256) void dist_kernel(
    const float* __restrict__ X, const float* __restrict__ Y,
    uint32* __restrict__ Dsk)
{
    __shared__ __align__(16) float Xs[128][68];
    __shared__ __align__(16) float Ys[64][68];

    const int b  = blockIdx.z;
    const int n0 = blockIdx.y * 128;
    const int m0 = blockIdx.x * 64;
    const int tid = threadIdx.x;

    const float* Xg = X + ((size_t)b * Nc + n0) * DFc;
    const float* Yg = Y + ((size_t)b * Mc + m0) * DFc;

    // X rows stored k-rotated by 4*n (mod 64): the 4 ty-adjacent rows read in
    // one xv gather land on banks {0,8,16,24} instead of one bank (was 4-way).
#pragma unroll
    for (int it = 0; it < 8; ++it) {
        int e4 = it * 256 + tid;
        int n = e4 >> 4, k = (e4 & 15) * 4;
        *(float4*)&Xs[n][(k + 4 * n) & 63] = *(const float4*)&Xg[e4 * 4];
    }
#pragma unroll
    for (int it = 0; it < 4; ++it) {
        int e4 = it * 256 + tid;
        int n = e4 >> 4, k = (e4 & 15) * 4;
        *(float4*)&Ys[n][k] = *(const float4*)&Yg[e4 * 4];
    }
    __syncthreads();

    const int tx = tid & 15;
    const int ty = tid >> 4;

    float acc[8][4];
#pragma unroll
    for (int a = 0; a < 8; ++a)
#pragma unroll
        for (int c = 0; c < 4; ++c) acc[a][c] = 0.0f;

#pragma unroll
    for (int k4 = 0; k4 < 16; ++k4) {
        float4 xv[8], yv[4];
#pragma unroll
        for (int a = 0; a < 8; ++a) {
            int r = ty + 16 * a;
            xv[a] = *(const float4*)&Xs[r][(k4 * 4 + 4 * r) & 63];
        }
#pragma unroll
        for (int c = 0; c < 4; ++c)
            yv[c] = *(const float4*)&Ys[tx + 16 * c][k4 * 4];
#pragma unroll
        for (int a = 0; a < 8; ++a) {
#pragma unroll
            for (int c = 0; c < 4; ++c) {
                float d0 = xv[a].x - yv[c].x;
                float d1 = xv[a].y - yv[c].y;
                float d2 = xv[a].z - yv[c].z;
                float d3 = xv[a].w - yv[c].w;
                acc[a][c] = fmaf(d0, d0,
                            fmaf(d1, d1,
                            fmaf(d2, d2,
                            fmaf(d3, d3, acc[a][c]))));
            }
        }
    }
    __syncthreads();   // done reading Xs/Ys; alias Xs as Ct

    // Ct[128][66]: row stride 66 -> skew reads below have lane bank-stride 1
    float* Ct = (float*)Xs;
#pragma unroll
    for (int a = 0; a < 8; ++a) {
        int r = ty + 16 * a;
#pragma unroll
        for (int c = 0; c < 4; ++c)
            Ct[r * 66 + tx + 16 * c] = acc[a][c];
    }
    __syncthreads();

    const int l  = tid & 63;
    const int pq = tid >> 6;   // 0..3
#pragma unroll
    for (int w2 = 0; w2 < 2; ++w2) {
        uint4* outt = (uint4*)Dsk +
            (((size_t)b * 8 + (2 * blockIdx.y + w2)) * 8 + blockIdx.x) * 1024;
        const float* Crow = Ct + (w2 * 64 + l) * 66;
#pragma unroll
        for (int it = 0; it < 4; ++it) {
            int pg = pq + 4 * it;
            int c0 = 8 * pg - l;
            uint32 u[4];
#pragma unroll
            for (int e = 0; e < 4; ++e) {
                float f0 = Crow[min(max(c0 + 2 * e,     0), 63)] * LOG2E_F;
                float f1 = Crow[min(max(c0 + 2 * e + 1, 0), 63)] * LOG2E_F;
                __half2 h = __floats2half2_rn(f0, f1);
                u[e] = *(uint32*)&h;
            }
            uint4 v; v.x = u[0]; v.y = u[1]; v.z = u[2]; v.w = u[3];
            outt[pg * 64 + l] = v;
        }
    }
}

// ---------------------------------------------------------------------------
// Kernel 2: tile-systolic soft-DTW scan (scaled domain: all R values x LOG2E).
// 1 block (8 waves) per batch; wave w owns rows 64w+1..64w+64 (lane l -> row
// 64w+l+1). 15 barrier-separated tile-steps. Inside a tile: 128 dpp+softmin
// steps; D via triple-buffered dwordx4 (12 pairs of vmcnt slack); frontier H
// read only in the first half (lane 0 is its only consumer and is inactive
// for s>64), written only in the second half (lane 63 inactive for s<64).
// ---------------------------------------------------------------------------
__global__ __launch_bounds__(512) void scan_kernel(
    const uint32* __restrict__ Dsk,
    const int* __restrict__ X_len, const int* __restrict__ Y_len,
    float* __restrict__ out)
{
    // [0..512] frontier row (R[i0][c], scaled), [513..663] benign-overread
    // scratch, [664..727] write dump for inactive-lane stores.
    __shared__ __align__(16) float Hs[728];

    const int tid = threadIdx.x;
    const int l = tid & 63, w = tid >> 6;
    const int b = blockIdx.x;

    const int xl = X_len[b], yl = Y_len[b];
    const int lxl = (xl - 1) & 63, wxl = (xl - 1) >> 6;
    const int Jcap = (yl - 1) >> 6;

    Hs[tid] = (tid == 0) ? 0.0f : BIGC;
    if (tid < 216) Hs[512 + tid] = BIGC;
    __syncthreads();

    const bool is63 = (l == 63);
    const int c1  = l + 1;     // lane's first active step (left-edge inject)
    const int c2s = l + 64;    // lane's right-edge step (Lf capture)
    const bool capture_wave = (w == wxl);
    float capv = BIGC;

    float Lf = BIGC;                      // left-edge column from tile J-1
    float corner = (w == 0) ? 0.0f : BIGC;

    for (int k = 0; k < 15; ++k) {
        int J = k - w;
        if (0 <= J && J < 8) {
            const int j0 = J << 6;
            // next tile's corner: stable now; clobbered by our lane63 at s=127
            float cornerNext = Hs[j0 + 64];
            float LfUp = dpp_shr1(corner, Lf);
            const uint4* tp4 = (const uint4*)Dsk +
                ((((size_t)b * 8 + w) * 8) + J) * 1024 + l;
            int scap = (capture_wave && J == Jcap && l == lxl)
                       ? (yl - j0 + lxl) : -1000;

            uint4 d0 = tp4[0];
            uint4 d1 = tp4[64];
            uint4 d2 = tp4[2 * 64];

            float cur = BIGC, diag = BIGC, Lfnext = BIGC, Lf0;
            int s = 1;

            // H for pairs 0..3 (step s consumes Hs[j0+s]; pair p: h1, g.x; g.y
            // is next pair's h1). 8B-aligned ds_read_b64 reads.
            float h1 = Hs[j0 + 1];
            float2 g0 = *(const float2*)&Hs[j0 + 2];
            float2 g1 = *(const float2*)&Hs[j0 + 4];
            float2 g2 = *(const float2*)&Hs[j0 + 6];
            float2 g3 = *(const float2*)&Hs[j0 + 8];

            // ---- first half: pg 0..7, s = 1..64 (left-edge inject, H reads,
            //      no frontier store: lane63 inactive) ----
            for (int m = 0; m < 8; ++m) {
                uint4 dn = tp4[(m + 3) * 64];          // pg 3..10
                int hb = j0 + 8 * m + 10;              // next group's H
                float2 n0v = *(const float2*)&Hs[hb];
                float2 n1v = *(const float2*)&Hs[hb + 2];
                float2 n2v = *(const float2*)&Hs[hb + 4];
                float2 n3v = *(const float2*)&Hs[hb + 6];

                const uint32 du[4] = {d0.x, d0.y, d0.z, d0.w};
                const float2 gg[4] = {g0, g1, g2, g3};
#pragma unroll
                for (int e = 0; e < 4; ++e) {
                    float2 df = __half22float2(*(const __half2*)&du[e]);
                    {   // step A (odd s), Hv = h1
                        float upc = dpp_shr1(h1, cur);
                        bool fst = (s == c1);
                        float dg = fst ? LfUp : diag;
                        float lt = fst ? Lf  : cur;
                        float mn = fminf(fminf(dg, upc), lt);
                        float sum = exp2f(mn - dg) + exp2f(mn - upc) + exp2f(mn - lt);
                        float val = (mn - log2f(sum)) + df.x;
                        capv = (s == scap) ? val : capv;
                        diag = upc; cur = val; ++s;
                    }
                    {   // step B (even s), Hv = gg[e].x
                        float upc = dpp_shr1(gg[e].x, cur);
                        bool fst = (s == c1);
                        float dg = fst ? LfUp : diag;
                        float lt = fst ? Lf  : cur;
                        float mn = fminf(fminf(dg, upc), lt);
                        float sum = exp2f(mn - dg) + exp2f(mn - upc) + exp2f(mn - lt);
                        float val = (mn - log2f(sum)) + df.y;
                        capv = (s == scap) ? val : capv;
                        diag = upc; cur = val; ++s;
                    }
                    h1 = gg[e].y;
                }
                d0 = d1; d1 = d2; d2 = dn;
                g0 = n0v; g1 = n1v; g2 = n2v; g3 = n3v;
            }
            Lf0 = cur;   // lane0's right-edge value (its s=64 output)

            // ---- second half: pg 8..15, s = 65..128 (no H reads: lane0 dead;
            //      frontier store every step) ----
            for (int m = 0; m < 8; ++m) {
                uint4 dn = tp4[min(m + 11, 15) * 64];
                const uint32 du[4] = {d0.x, d0.y, d0.z, d0.w};
#pragma unroll
                for (int e = 0; e < 4; ++e) {
                    float2 df = __half22float2(*(const __half2*)&du[e]);
#pragma unroll
                    for (int hstep = 0; hstep < 2; ++hstep) {
                        float Dv = hstep ? df.y : df.x;
                        float upc = dpp_shr1(cur, cur);   // lane0 value dead
                        float mn = fminf(fminf(diag, upc), cur);
                        float sum = exp2f(mn - diag) + exp2f(mn - upc) + exp2f(mn - cur);
                        float val = (mn - log2f(sum)) + Dv;
                        Lfnext = (s == c2s) ? val : Lfnext;
                        capv   = (s == scap) ? val : capv;
                        diag = upc; cur = val;
                        int idx = (is63 && s <= 127) ? (j0 - 63 + s) : (664 + l);
                        Hs[idx] = val;
                        ++s;
                    }
                }
                d0 = d1; d1 = d2; d2 = dn;
            }

            Lfnext = (l == 0) ? Lf0 : Lfnext;
            Lf = Lfnext;
            corner = cornerNext;
        }
        __syncthreads();
    }

    if (capture_wave) {
        float o = __int_as_float(
            __builtin_amdgcn_readlane(__float_as_int(capv), lxl));
        if (l == 0) out[b] = o * LN2_F;
    }
}

extern "C" void kernel_launch(void* const* d_in, const int* in_sizes, int n_in,
                              void* d_out, int out_size, void* d_ws, size_t ws_size,
                              hipStream_t stream)
{
    const float* X  = (const float*)d_in[0];
    const float* Y  = (const float*)d_in[1];
    const int*   xl = (const int*)d_in[2];
    const int*   yl = (const int*)d_in[3];
    float* out = (float*)d_out;
    uint32* Dsk = (uint32*)d_ws;   // 32 * 64 tiles * 16 KB = 33.5 MB

    dist_kernel<<<dim3(8, 4, Bc), 256, 0, stream>>>(X, Y, Dsk);
    scan_kernel<<<Bc, 512, 0, stream>>>(Dsk, xl, yl, out);
}